// Round 12
// baseline (143.797 us; speedup 1.0000x reference)
//
#include <hip/hip_runtime.h>
#include <math.h>

#define BB 1024
#define S 32
#define DIM 64
#define NREL 237
#define NENT 14541
#define SIGMA 0.1f

// ---- workspace layout (float offsets) ----
#define OFS_WR    0                       // 238*64  : Wr = relf_ext @ W_agg0 (row 237 = 0)
#define N_WR      (238*64)
#define OFS_WC0   15232                   // 64*237  : W_agg1 @ W_out[:237]
#define N_WC      (64*237)
#define OFS_WC1   (OFS_WC0 + N_WC)        // 64*237
#define OFS_BC    (OFS_WC1 + N_WC)        // 237
#define OFS_HC    (OFS_BC + 237)          // 64
#define OFS_A     45872                   // 14542*64 : per-entity aggregate (float4-aligned)

// gf LDS map (floats), gather phase (2 b's = 4 units):
//   s_v1   [0,8704)      4 units x 32 j x 68
//   s_r1   [8704,8832)   int
//   s_ent2 [8832,8960)   int
//   s_m1   [8960,9088)
//   s_ov   [9088,9344)   4 x 64 (persists into epilogue)
// epilogue aliases [0,2048): per half p: base=p*1024:
//   ymix[base,+240) outv[+240,+480) red[+480,+736) h[+736,+800)
// total 9344 floats = 37376 B -> 4 blocks/CU by LDS; 512 blocks need 2/CU
// -> ALL blocks resident in one round.
#define LDS_BYTES 37376

__device__ __forceinline__ float selu_f(float x) {
    const float alpha = 1.6732632423543772f;
    const float scale = 1.0507009873554805f;
    return scale * (x > 0.f ? x : alpha * expm1f(x));
}

// ---------- Kernel 1: Wr only ----------
__global__ __launch_bounds__(256) void pre_wr_kernel(
    const float* __restrict__ rel_feat, const float* __restrict__ W0,
    float* __restrict__ ws) {
    int idx = blockIdx.x * 256 + threadIdx.x;
    if (idx < 238 * 64) {
        int r = idx >> 6, o = idx & 63;
        float acc = 0.f;
        if (r < NREL) {
#pragma unroll 8
            for (int d = 0; d < 64; ++d)
                acc += rel_feat[r * 64 + d] * W0[d * 64 + o];
        }
        ws[OFS_WR + idx] = acc;            // row 237 stays 0
    }
}

// ---------- Kernel 2 (fused): agg (L2-gather-bound) + Wc/bc/hc (FMA-bound) ----------
__global__ __launch_bounds__(512) void mid_kernel(
    const int* __restrict__ e2e_tab, const int* __restrict__ e2r,
    const float* __restrict__ W1, const float* __restrict__ b1,
    const float* __restrict__ W_out, const float* __restrict__ b_out,
    const float* __restrict__ mW1, const float* __restrict__ mb1,
    float* __restrict__ ws) {
    __shared__ int   s_r[1024];
    __shared__ float red[512];
    int blk = blockIdx.x;
    const int tid = threadIdx.x;

    if (blk < 455) {                       // agg: 32 entities per block
        const int grp = tid >> 4, c = tid & 15;
        const int ent = blk * 32 + grp;
        const bool ok = ent < (NENT + 1);
        if (ok) {
            int ea = e2e_tab[ent * S + c];
            int eb = e2e_tab[ent * S + 16 + c];
            s_r[grp * 32 + c] = e2r[ea];
            s_r[grp * 32 + 16 + c] = e2r[eb];
        }
        __syncthreads();
        if (ok) {
            const float4* Wr4 = (const float4*)(ws + OFS_WR);
            const int* rr = &s_r[grp * 32];
            float4 acc = make_float4(0.f, 0.f, 0.f, 0.f);
#pragma unroll
            for (int s = 0; s < 32; ++s) {
                float4 v = Wr4[rr[s] * 16 + c];
                acc.x += v.x; acc.y += v.y; acc.z += v.z; acc.w += v.w;
            }
            ((float4*)(ws + OFS_A))[ent * 16 + c] = acc;
        }
        return;
    }
    blk -= 455;
    if (blk < 512) {                       // Wc0/Wc1: 8-way k-split
        int half = blk >> 8;
        int lb = blk & 255;
        int o = lb >> 2, ct = lb & 3;
        int cl = tid & 63, q = tid >> 6;
        int c = ct * 64 + cl;
        const float* Wsrc = W_out + half * 237 * 237;
        float acc = 0.f;
        if (c < NREL) {
            int k0 = q * 30, k1 = (q == 7) ? 237 : (k0 + 30);
#pragma unroll 4
            for (int k = k0; k < k1; ++k)
                acc += W1[o * 237 + k] * Wsrc[k * 237 + c];
        }
        red[tid] = acc;
        __syncthreads();
        if (q == 0 && c < NREL) {
            float s = 0.f;
#pragma unroll
            for (int qq = 0; qq < 8; ++qq) s += red[qq * 64 + cl];
            ws[(half ? OFS_WC1 : OFS_WC0) + o * 237 + c] = s;
        }
        return;
    }
    blk -= 512;
    if (blk < 4) {                         // bc[c]
        int cl = tid & 63, q = tid >> 6;
        int c = blk * 64 + cl;
        float acc = 0.f;
        if (c < NREL) {
            int k0 = q * 30, k1 = (q == 7) ? 237 : (k0 + 30);
#pragma unroll 4
            for (int k = k0; k < k1; ++k)
                acc += b1[k] * (W_out[k * 237 + c] + W_out[(237 + k) * 237 + c]);
        }
        red[tid] = acc;
        __syncthreads();
        if (q == 0 && c < NREL) {
            float s = b_out[c];
#pragma unroll
            for (int qq = 0; qq < 8; ++qq) s += red[qq * 64 + cl];
            ws[OFS_BC + c] = s;
        }
        return;
    }
    // hc[w]
    {
        int w = tid & 63, q = tid >> 6;
        int k0 = q * 30, k1 = (q == 7) ? 237 : (k0 + 30);
        float acc = 0.f;
#pragma unroll 4
        for (int k = k0; k < k1; ++k)
            acc += b1[k] * mW1[k * 64 + w];
        red[tid] = acc;
        __syncthreads();
        if (q == 0) {
            float s = mb1[w];
#pragma unroll
            for (int qq = 0; qq < 8; ++qq) s += red[qq * 64 + w];
            ws[OFS_HC + w] = s;
        }
    }
}

// ---------- Kernel GF: 2 b's per block, 512 threads; half p owns b=bb+p ----------
__global__ __launch_bounds__(512) void gf_kernel(
    const int* __restrict__ ep, const int* __restrict__ te_arr,
    const int* __restrict__ e2e_tab, const int* __restrict__ e2ent,
    const int* __restrict__ e2r, const float* __restrict__ b0,
    const float* __restrict__ t_arr, const float* __restrict__ eps,
    const float* __restrict__ W1, const float* __restrict__ mW1,
    const float* __restrict__ mW2, const float* __restrict__ mb2,
    const float* __restrict__ mW3, const float* __restrict__ mb3,
    const float* __restrict__ mW4, const float* __restrict__ mb4,
    const float* __restrict__ ws, float* __restrict__ out) {
    extern __shared__ float smem[];
    float* s_v1   = smem;                  // 4*32*68
    int*   s_r1   = (int*)(smem + 8704);
    int*   s_ent2 = (int*)(smem + 8832);
    float* s_m1   = smem + 8960;
    float* s_ov   = smem + 9088;           // 4 x 64

    const int tid = threadIdx.x;
    const int bb = blockIdx.x * 2;
    const int grp = tid >> 4;              // 32 groups of 16 threads
    const int c = tid & 15;
    const int te0 = te_arr[bb];
    const int te1 = te_arr[bb + 1];
    const float4* Wr4 = (const float4*)(ws + OFS_WR);
    const float4* A4  = (const float4*)(ws + OFS_A);
    const float4 b0v  = ((const float4*)b0)[c];
    const float4 wrte0 = Wr4[e2r[te0] * 16 + c];
    const float4 wrte1 = Wr4[e2r[te1] * 16 + c];

    // stage-1 for all 4 (b,side) units
    if (tid < 128) {
        int u = tid >> 5, s = tid & 31;
        int b_ = bb + (u >> 1);
        int te_u = (u >> 1) ? te1 : te0;
        int ent = ep[b_ * 2 + (u & 1)];
        int e1 = e2e_tab[ent * S + s];
        s_r1[u * 32 + s] = e2r[e1];
        s_m1[u * 32 + s] = (e1 != te_u) ? 1.0f : 0.0f;
        s_ent2[u * 32 + s] = e2ent[e1];
    }
    __syncthreads();

    const float inv = 1.0f / 32.0f;
#pragma unroll
    for (int u = 0; u < 4; ++u) {
        const int te_u = (u >> 1) ? te1 : te0;
        const float4 wrte = (u >> 1) ? wrte1 : wrte0;
        const int j = grp;
        const int ent2 = s_ent2[u * 32 + j];
        int e2a = e2e_tab[ent2 * S + c];
        int e2b = e2e_tab[ent2 * S + 16 + c];
        int cnt = (e2a == te_u) + (e2b == te_u);
        cnt += __shfl_xor(cnt, 1);
        cnt += __shfl_xor(cnt, 2);
        cnt += __shfl_xor(cnt, 4);
        cnt += __shfl_xor(cnt, 8);
        float4 a4   = A4[ent2 * 16 + c];
        float4 self = Wr4[s_r1[u * 32 + j] * 16 + c];
        float fc = (float)cnt;
        float m = s_m1[u * 32 + j];
        float4 r;
        r.x = fmaxf(self.x + (a4.x - fc * wrte.x) * inv + b0v.x, 0.f) * m;
        r.y = fmaxf(self.y + (a4.y - fc * wrte.y) * inv + b0v.y, 0.f) * m;
        r.z = fmaxf(self.z + (a4.z - fc * wrte.z) * inv + b0v.z, 0.f) * m;
        r.w = fmaxf(self.w + (a4.w - fc * wrte.w) * inv + b0v.w, 0.f) * m;
        *((float4*)&s_v1[(u * 32 + j) * 68 + c * 4]) = r;
    }
    __syncthreads();
    if (tid < 256) {
        int u = tid >> 6, w = tid & 63;
        float sum = 0.f;
#pragma unroll 8
        for (int j = 0; j < 32; ++j) sum += s_v1[(u * 32 + j) * 68 + w];
        s_ov[u * 64 + w] = sum * inv;
    }
    __syncthreads();

    // ---------------- epilogue: half p owns b = bb+p ----------------
    const int p  = tid >> 8;
    const int lt = tid & 255;
    float* s_ymix = smem + p * 1024;       // 240
    float* s_outv = smem + p * 1024 + 240; // 240
    float* s_red  = smem + p * 1024 + 480; // 256
    float* s_h    = smem + p * 1024 + 736; // 64
    const float tb = t_arr[bb + p];
    const float* ovp = s_ov + p * 128;     // [0,64)=side0, [64,128)=side1
    const float* Wc0 = ws + OFS_WC0;
    const float* Wc1 = ws + OFS_WC1;
    const float* bc = ws + OFS_BC;
    const float* hc = ws + OFS_HC;

    // ymix[k] (omix folded in) and outv[c], one pass
    if (lt < NREL) {
        float y = 0.f, a = bc[lt];
        const float om = 1.f - tb;
#pragma unroll 4
        for (int d = 0; d < 64; ++d) {
            float o0 = ovp[d], o1 = ovp[64 + d];
            y += (om * o0 + tb * o1) * W1[d * 237 + lt];
            a += o0 * Wc0[d * 237 + lt] + o1 * Wc1[d * 237 + lt];
        }
        s_ymix[lt] = y;
        s_outv[lt] = a;
    }
    __syncthreads();

    // h1: k-split 4 (256 = 64 x 4)
    {
        int w = lt & 63, q = lt >> 6;
        int k0 = q * 60, k1 = (q == 3) ? 237 : (k0 + 60);
        const float* e = eps + (bb + p) * 237;
        float a = 0.f;
#pragma unroll 4
        for (int k = k0; k < k1; ++k)
            a += (SIGMA * e[k] + s_ymix[k]) * mW1[k * 64 + w];
        s_red[lt] = a;
    }
    __syncthreads();
    if (lt < 64) {
        float h = hc[lt] + tb * mW1[237 * 64 + lt]
                + s_red[lt] + s_red[64 + lt] + s_red[128 + lt] + s_red[192 + lt];
        s_h[lt] = selu_f(h);
    }
    __syncthreads();

    // h2: d-split 4
    {
        int w = lt & 63, q = lt >> 6;
        float a = 0.f;
#pragma unroll
        for (int d = q * 16; d < q * 16 + 16; ++d)
            a += s_h[d] * mW2[d * 64 + w];
        s_red[lt] = a;
    }
    __syncthreads();
    if (lt < 64) {
        float v = mb2[lt] + s_red[lt] + s_red[64 + lt] + s_red[128 + lt] + s_red[192 + lt];
        s_h[lt] = selu_f(v);
    }
    __syncthreads();

    // h3: d-split 4
    {
        int w = lt & 63, q = lt >> 6;
        float a = 0.f;
#pragma unroll
        for (int d = q * 16; d < q * 16 + 16; ++d)
            a += s_h[d] * mW3[d * 64 + w];
        s_red[lt] = a;
    }
    __syncthreads();
    if (lt < 64) {
        float v = mb3[lt] + s_red[lt] + s_red[64 + lt] + s_red[128 + lt] + s_red[192 + lt];
        s_h[lt] = selu_f(v);
    }
    __syncthreads();

    // vt and final product
    if (lt < NREL) {
        float a = mb4[lt];
#pragma unroll 4
        for (int w = 0; w < 64; ++w)
            a += s_h[w] * mW4[w * 237 + lt];
        out[(bb + p) * 237 + lt] = s_outv[lt] * a;
    }
}

extern "C" void kernel_launch(void* const* d_in, const int* in_sizes, int n_in,
                              void* d_out, int out_size, void* d_ws, size_t ws_size,
                              hipStream_t stream) {
    const int* ep       = (const int*)d_in[0];
    const int* te       = (const int*)d_in[1];
    // d_in[2] = labels : dead code in the reference
    const int* e2e      = (const int*)d_in[3];
    const int* e2ent    = (const int*)d_in[4];
    const int* e2r      = (const int*)d_in[5];
    const float* t      = (const float*)d_in[6];
    const float* eps    = (const float*)d_in[7];
    const float* relf   = (const float*)d_in[8];
    const float* W0     = (const float*)d_in[9];
    const float* b0     = (const float*)d_in[10];
    const float* W1     = (const float*)d_in[11];
    const float* b1     = (const float*)d_in[12];
    const float* W_out  = (const float*)d_in[13];
    const float* b_out  = (const float*)d_in[14];
    const float* mW1    = (const float*)d_in[15];
    const float* mb1    = (const float*)d_in[16];
    const float* mW2    = (const float*)d_in[17];
    const float* mb2    = (const float*)d_in[18];
    const float* mW3    = (const float*)d_in[19];
    const float* mb3    = (const float*)d_in[20];
    const float* mW4    = (const float*)d_in[21];
    const float* mb4    = (const float*)d_in[22];
    float* ws  = (float*)d_ws;
    float* out = (float*)d_out;

    hipLaunchKernelGGL(pre_wr_kernel, dim3(60), dim3(256), 0, stream,
                       relf, W0, ws);
    hipLaunchKernelGGL(mid_kernel, dim3(972), dim3(512), 0, stream,
                       e2e, e2r, W1, b1, W_out, b_out, mW1, mb1, ws);
    hipLaunchKernelGGL(gf_kernel, dim3(BB / 2), dim3(512), LDS_BYTES, stream,
                       ep, te, e2e, e2ent, e2r, b0,
                       t, eps, W1, mW1, mW2, mb2, mW3, mb3, mW4, mb4, ws, out);
}

// Round 14
// 141.597 us; speedup vs baseline: 1.0155x; 1.0155x over previous
//
#include <hip/hip_runtime.h>
#include <math.h>

#define BB 1024
#define S 32
#define DIM 64
#define NREL 237
#define NENT 14541
#define SIGMA 0.1f

// ---- workspace layout (float offsets) ----
#define OFS_WR    0                       // 238*64  : Wr = relf_ext @ W_agg0 (row 237 = 0)
#define N_WR      (238*64)
#define OFS_WC0   15232                   // 64*237  : W_agg1 @ W_out[:237]
#define N_WC      (64*237)
#define OFS_WC1   (OFS_WC0 + N_WC)        // 64*237
#define OFS_BC    (OFS_WC1 + N_WC)        // 237
#define OFS_HC    (OFS_BC + 237)          // 64
#define OFS_A     45872                   // 14542*64 : per-entity aggregate (float4-aligned)

// gf LDS map (floats):
//   s_v1   [0,4352)      2 units x 32 j x 68
//   s_r1   [4352,4416)   int
//   s_ent2 [4416,4480)   int
//   s_m1   [4480,4544)
//   s_ov   [4544,4672)   2 x 64 (persists into epilogue)
// epilogue aliases [0,1600): s_ymix[0,240) s_outv[240,480) s_red[480,992)
//   s_h[992,1056) s_omix[1056,1120) s_vp[1120,1600)
// total 4672 floats = 18688 B -> 4 blocks x 8 waves = 32 waves/CU (max).
#define LDS_BYTES 18688

__device__ __forceinline__ float selu_f(float x) {
    const float alpha = 1.6732632423543772f;
    const float scale = 1.0507009873554805f;
    return scale * (x > 0.f ? x : alpha * expm1f(x));
}

// ---------- Kernel 1: Wr only (everything downstream depends on this) ----------
__global__ __launch_bounds__(256) void pre_wr_kernel(
    const float* __restrict__ rel_feat, const float* __restrict__ W0,
    float* __restrict__ ws) {
    int idx = blockIdx.x * 256 + threadIdx.x;
    if (idx < 238 * 64) {
        int r = idx >> 6, o = idx & 63;
        float acc = 0.f;
        if (r < NREL) {
#pragma unroll 8
            for (int d = 0; d < 64; ++d)
                acc += rel_feat[r * 64 + d] * W0[d * 64 + o];
        }
        ws[OFS_WR + idx] = acc;            // row 237 stays 0
    }
}

// ---------- Kernel 2 (fused): agg (L2-gather-bound) + Wc/bc/hc (FMA-bound) ----------
// The two workloads are independent (both depend only on Wr / raw inputs) and
// co-schedule on the same CUs: latency of one hides under compute of the other.
__global__ __launch_bounds__(512) void mid_kernel(
    const int* __restrict__ e2e_tab, const int* __restrict__ e2r,
    const float* __restrict__ W1, const float* __restrict__ b1,
    const float* __restrict__ W_out, const float* __restrict__ b_out,
    const float* __restrict__ mW1, const float* __restrict__ mb1,
    float* __restrict__ ws) {
    __shared__ int   s_r[1024];
    __shared__ float red[512];
    int blk = blockIdx.x;
    const int tid = threadIdx.x;

    if (blk < 455) {                       // agg: 32 entities per block
        const int grp = tid >> 4, c = tid & 15;
        const int ent = blk * 32 + grp;
        const bool ok = ent < (NENT + 1);
        if (ok) {
            int ea = e2e_tab[ent * S + c];
            int eb = e2e_tab[ent * S + 16 + c];
            s_r[grp * 32 + c] = e2r[ea];
            s_r[grp * 32 + 16 + c] = e2r[eb];
        }
        __syncthreads();
        if (ok) {
            const float4* Wr4 = (const float4*)(ws + OFS_WR);
            const int* rr = &s_r[grp * 32];
            float4 acc = make_float4(0.f, 0.f, 0.f, 0.f);
#pragma unroll
            for (int s = 0; s < 32; ++s) {
                float4 v = Wr4[rr[s] * 16 + c];
                acc.x += v.x; acc.y += v.y; acc.z += v.z; acc.w += v.w;
            }
            ((float4*)(ws + OFS_A))[ent * 16 + c] = acc;
        }
        return;
    }
    blk -= 455;
    if (blk < 512) {                       // Wc0/Wc1: 8-way k-split (chain ~30)
        int half = blk >> 8;
        int lb = blk & 255;
        int o = lb >> 2, ct = lb & 3;
        int cl = tid & 63, q = tid >> 6;
        int c = ct * 64 + cl;
        const float* Wsrc = W_out + half * 237 * 237;
        float acc = 0.f;
        if (c < NREL) {
            int k0 = q * 30, k1 = (q == 7) ? 237 : (k0 + 30);
#pragma unroll 4
            for (int k = k0; k < k1; ++k)
                acc += W1[o * 237 + k] * Wsrc[k * 237 + c];
        }
        red[tid] = acc;
        __syncthreads();
        if (q == 0 && c < NREL) {
            float s = 0.f;
#pragma unroll
            for (int qq = 0; qq < 8; ++qq) s += red[qq * 64 + cl];
            ws[(half ? OFS_WC1 : OFS_WC0) + o * 237 + c] = s;
        }
        return;
    }
    blk -= 512;
    if (blk < 4) {                         // bc[c]
        int cl = tid & 63, q = tid >> 6;
        int c = blk * 64 + cl;
        float acc = 0.f;
        if (c < NREL) {
            int k0 = q * 30, k1 = (q == 7) ? 237 : (k0 + 30);
#pragma unroll 4
            for (int k = k0; k < k1; ++k)
                acc += b1[k] * (W_out[k * 237 + c] + W_out[(237 + k) * 237 + c]);
        }
        red[tid] = acc;
        __syncthreads();
        if (q == 0 && c < NREL) {
            float s = b_out[c];
#pragma unroll
            for (int qq = 0; qq < 8; ++qq) s += red[qq * 64 + cl];
            ws[OFS_BC + c] = s;
        }
        return;
    }
    // hc[w]
    {
        int w = tid & 63, q = tid >> 6;
        int k0 = q * 30, k1 = (q == 7) ? 237 : (k0 + 30);
        float acc = 0.f;
#pragma unroll 4
        for (int k = k0; k < k1; ++k)
            acc += b1[k] * mW1[k * 64 + w];
        red[tid] = acc;
        __syncthreads();
        if (q == 0) {
            float s = mb1[w];
#pragma unroll
            for (int qq = 0; qq < 8; ++qq) s += red[qq * 64 + w];
            ws[OFS_HC + w] = s;
        }
    }
}

// ---------- Kernel GF: gather-from-A + epilogue, 1 b per block, 512 threads ----------
__global__ __launch_bounds__(512, 8) void gf_kernel(
    const int* __restrict__ ep, const int* __restrict__ te_arr,
    const int* __restrict__ e2e_tab, const int* __restrict__ e2ent,
    const int* __restrict__ e2r, const float* __restrict__ b0,
    const float* __restrict__ t_arr, const float* __restrict__ eps,
    const float* __restrict__ W1, const float* __restrict__ mW1,
    const float* __restrict__ mW2, const float* __restrict__ mb2,
    const float* __restrict__ mW3, const float* __restrict__ mb3,
    const float* __restrict__ mW4, const float* __restrict__ mb4,
    const float* __restrict__ ws, float* __restrict__ out) {
    extern __shared__ float smem[];
    float* s_v1   = smem;                  // 2*32*68
    int*   s_r1   = (int*)(smem + 4352);
    int*   s_ent2 = (int*)(smem + 4416);
    float* s_m1   = smem + 4480;
    float* s_ov   = smem + 4544;

    const int tid = threadIdx.x;
    const int b = blockIdx.x;
    const int grp = tid >> 4;              // 32 groups of 16 threads
    const int c = tid & 15;
    const int te = te_arr[b];
    const int rte = e2r[te];
    const float4* Wr4 = (const float4*)(ws + OFS_WR);
    const float4* A4  = (const float4*)(ws + OFS_A);
    const float4 b0v  = ((const float4*)b0)[c];
    const float4 wrte = Wr4[rte * 16 + c];

    // stage-1 for both sides
    if (tid < 64) {
        int u = tid >> 5, s = tid & 31;
        int ent = ep[b * 2 + u];
        int e1 = e2e_tab[ent * S + s];
        s_r1[u * 32 + s] = e2r[e1];
        s_m1[u * 32 + s] = (e1 != te) ? 1.0f : 0.0f;
        s_ent2[u * 32 + s] = e2ent[e1];
    }
    __syncthreads();

    const float inv = 1.0f / 32.0f;
#pragma unroll
    for (int u = 0; u < 2; ++u) {
        const int j = grp;
        const int ent2 = s_ent2[u * 32 + j];
        int e2a = e2e_tab[ent2 * S + c];
        int e2b = e2e_tab[ent2 * S + 16 + c];
        int cnt = (e2a == te) + (e2b == te);
        cnt += __shfl_xor(cnt, 1);
        cnt += __shfl_xor(cnt, 2);
        cnt += __shfl_xor(cnt, 4);
        cnt += __shfl_xor(cnt, 8);
        float4 a4   = A4[ent2 * 16 + c];
        float4 self = Wr4[s_r1[u * 32 + j] * 16 + c];
        float fc = (float)cnt;
        float m = s_m1[u * 32 + j];
        float4 r;
        r.x = fmaxf(self.x + (a4.x - fc * wrte.x) * inv + b0v.x, 0.f) * m;
        r.y = fmaxf(self.y + (a4.y - fc * wrte.y) * inv + b0v.y, 0.f) * m;
        r.z = fmaxf(self.z + (a4.z - fc * wrte.z) * inv + b0v.z, 0.f) * m;
        r.w = fmaxf(self.w + (a4.w - fc * wrte.w) * inv + b0v.w, 0.f) * m;
        *((float4*)&s_v1[(u * 32 + j) * 68 + c * 4]) = r;
    }
    __syncthreads();
    if (tid < 128) {
        int u = tid >> 6, w = tid & 63;
        float sum = 0.f;
#pragma unroll 8
        for (int j = 0; j < 32; ++j) sum += s_v1[(u * 32 + j) * 68 + w];
        s_ov[u * 64 + w] = sum * inv;
    }
    __syncthreads();

    // ---------------- epilogue ----------------
    float* s_ymix = smem;          // 240
    float* s_outv = smem + 240;    // 240
    float* s_red  = smem + 480;    // 512
    float* s_h    = smem + 992;    // 64
    float* s_omix = smem + 1056;   // 64
    float* s_vp   = smem + 1120;   // 2*240
    const float tb = t_arr[b];
    const float* Wc0 = ws + OFS_WC0;
    const float* Wc1 = ws + OFS_WC1;
    const float* bc = ws + OFS_BC;
    const float* hc = ws + OFS_HC;

    if (tid < 64)
        s_omix[tid] = (1.f - tb) * s_ov[tid] + tb * s_ov[64 + tid];
    __syncthreads();

    if (tid < 256) {
        if (tid < NREL) {
            float y = 0.f;
#pragma unroll 4
            for (int d = 0; d < 64; ++d)
                y += s_omix[d] * W1[d * 237 + tid];
            s_ymix[tid] = y;
        }
    } else {
        int cc = tid - 256;
        if (cc < NREL) {
            float a = bc[cc];
#pragma unroll 4
            for (int d = 0; d < 64; ++d)
                a += s_ov[d] * Wc0[d * 237 + cc] + s_ov[64 + d] * Wc1[d * 237 + cc];
            s_outv[cc] = a;
        }
    }
    __syncthreads();

    // h1: k-split 8
    {
        int w = tid & 63, q = tid >> 6;
        int k0 = q * 30, k1 = (q == 7) ? 237 : (k0 + 30);
        const float* e = eps + b * 237;
        float a = 0.f;
#pragma unroll 4
        for (int k = k0; k < k1; ++k)
            a += (SIGMA * e[k] + s_ymix[k]) * mW1[k * 64 + w];
        s_red[tid] = a;
    }
    __syncthreads();
    if (tid < 64) {
        float h = hc[tid] + tb * mW1[237 * 64 + tid];
#pragma unroll
        for (int q = 0; q < 8; ++q) h += s_red[q * 64 + tid];
        s_h[tid] = selu_f(h);
    }
    __syncthreads();

    // h2: d-split 8
    {
        int w = tid & 63, q = tid >> 6;
        float a = 0.f;
#pragma unroll
        for (int d = q * 8; d < q * 8 + 8; ++d)
            a += s_h[d] * mW2[d * 64 + w];
        s_red[tid] = a;
    }
    __syncthreads();
    if (tid < 64) {
        float v = mb2[tid];
#pragma unroll
        for (int q = 0; q < 8; ++q) v += s_red[q * 64 + tid];
        s_h[tid] = selu_f(v);
    }
    __syncthreads();

    // h3: d-split 8
    {
        int w = tid & 63, q = tid >> 6;
        float a = 0.f;
#pragma unroll
        for (int d = q * 8; d < q * 8 + 8; ++d)
            a += s_h[d] * mW3[d * 64 + w];
        s_red[tid] = a;
    }
    __syncthreads();
    if (tid < 64) {
        float v = mb3[tid];
#pragma unroll
        for (int q = 0; q < 8; ++q) v += s_red[q * 64 + tid];
        s_h[tid] = selu_f(v);
    }
    __syncthreads();

    // vt: k-split 2, then final product
    {
        int half = tid >> 8, cc = tid & 255;
        if (cc < NREL) {
            float a = 0.f;
#pragma unroll 4
            for (int w = half * 32; w < half * 32 + 32; ++w)
                a += s_h[w] * mW4[w * 237 + cc];
            s_vp[half * 240 + cc] = a;
        }
    }
    __syncthreads();
    if (tid < NREL)
        out[b * 237 + tid] = s_outv[tid] * (mb4[tid] + s_vp[tid] + s_vp[240 + tid]);
}

extern "C" void kernel_launch(void* const* d_in, const int* in_sizes, int n_in,
                              void* d_out, int out_size, void* d_ws, size_t ws_size,
                              hipStream_t stream) {
    const int* ep       = (const int*)d_in[0];
    const int* te       = (const int*)d_in[1];
    // d_in[2] = labels : dead code in the reference
    const int* e2e      = (const int*)d_in[3];
    const int* e2ent    = (const int*)d_in[4];
    const int* e2r      = (const int*)d_in[5];
    const float* t      = (const float*)d_in[6];
    const float* eps    = (const float*)d_in[7];
    const float* relf   = (const float*)d_in[8];
    const float* W0     = (const float*)d_in[9];
    const float* b0     = (const float*)d_in[10];
    const float* W1     = (const float*)d_in[11];
    const float* b1     = (const float*)d_in[12];
    const float* W_out  = (const float*)d_in[13];
    const float* b_out  = (const float*)d_in[14];
    const float* mW1    = (const float*)d_in[15];
    const float* mb1    = (const float*)d_in[16];
    const float* mW2    = (const float*)d_in[17];
    const float* mb2    = (const float*)d_in[18];
    const float* mW3    = (const float*)d_in[19];
    const float* mb3    = (const float*)d_in[20];
    const float* mW4    = (const float*)d_in[21];
    const float* mb4    = (const float*)d_in[22];
    float* ws  = (float*)d_ws;
    float* out = (float*)d_out;

    hipLaunchKernelGGL(pre_wr_kernel, dim3(60), dim3(256), 0, stream,
                       relf, W0, ws);
    hipLaunchKernelGGL(mid_kernel, dim3(972), dim3(512), 0, stream,
                       e2e, e2r, W1, b1, W_out, b_out, mW1, mb1, ws);
    hipLaunchKernelGGL(gf_kernel, dim3(BB), dim3(512), LDS_BYTES, stream,
                       ep, te, e2e, e2ent, e2r, b0,
                       t, eps, W1, mW1, mW2, mb2, mW3, mb3, mW4, mb4, ws, out);
}